// Round 1
// baseline (338.683 us; speedup 1.0000x reference)
//
#include <hip/hip_runtime.h>
#include <hip/hip_bf16.h>
#include <math.h>

#define BSZ 2
#define NQ 4096
#define DIM 768
#define HEADS 6
#define POINTS 4
#define HD 128
#define HW_DIM 64
#define NV (HW_DIM*HW_DIM)
#define M_TOTAL (BSZ*NQ)   // 8192

typedef __attribute__((ext_vector_type(8))) short bf16x8;
typedef __attribute__((ext_vector_type(4))) float f32x4;

__device__ inline short f2bf(float f) {
    union { float f; unsigned u; } v; v.f = f;
    unsigned r = v.u + 0x7fffu + ((v.u >> 16) & 1u);
    return (short)(r >> 16);
}

// ---------------- LayerNorm: one block per row (768 elems, 256 threads) ----
__global__ __launch_bounds__(256) void ln_kernel(const float* __restrict__ x,
        const float* __restrict__ w, const float* __restrict__ b,
        float* __restrict__ q) {
    int row = blockIdx.x;
    int tid = threadIdx.x;
    const float* xr = x + (size_t)row * DIM;
    float v0 = xr[tid], v1 = xr[tid + 256], v2 = xr[tid + 512];
    float s  = v0 + v1 + v2;
    float ss = v0*v0 + v1*v1 + v2*v2;
    __shared__ float red[256], red2[256];
    red[tid] = s; red2[tid] = ss;
    __syncthreads();
    for (int st = 128; st > 0; st >>= 1) {
        if (tid < st) { red[tid] += red[tid + st]; red2[tid] += red2[tid + st]; }
        __syncthreads();
    }
    float mean = red[0] * (1.0f / DIM);
    float var  = red2[0] * (1.0f / DIM) - mean * mean;
    float rstd = rsqrtf(var + 1e-6f);
    float* qr = q + (size_t)row * DIM;
    qr[tid]       = (v0 - mean) * rstd * w[tid]       + b[tid];
    qr[tid + 256] = (v1 - mean) * rstd * w[tid + 256] + b[tid + 256];
    qr[tid + 512] = (v2 - mean) * rstd * w[tid + 512] + b[tid + 512];
}

// ---------------- Generic bf16-MFMA GEMM: C = A(MxK) * B(KxN) + bias -------
// optional epilogue: C = resid + gamma * (A*B + bias)
// block = 256 (4 waves), tile 64(M) x 64(N), BK = 32
__global__ __launch_bounds__(256) void gemm_kernel(
        const float* __restrict__ A, const float* __restrict__ B,
        const float* __restrict__ bias, float* __restrict__ C,
        int M, int N, int K,
        const float* __restrict__ resid, const float* __restrict__ gamma) {
    __shared__ short As[64 * 32];
    __shared__ short Bt[64 * 32];
    int tid  = threadIdx.x;
    int n0   = blockIdx.x * 64;
    int row0 = blockIdx.y * 64;
    int wave = tid >> 6, lane = tid & 63;
    int lm = lane & 15, quad = lane >> 4;

    f32x4 acc[4];
    for (int i = 0; i < 4; i++) acc[i] = (f32x4){0.f, 0.f, 0.f, 0.f};

    int arow = tid >> 2, acol = (tid & 3) << 3;   // A staging: 64 rows x 32 cols
    int bk   = tid >> 3, bn   = (tid & 7) << 3;   // B staging: 32 k x 64 n

    for (int k0 = 0; k0 < K; k0 += 32) {
        // stage A tile (fp32 -> bf16)
        const float* ag = A + (size_t)(row0 + arow) * K + k0 + acol;
        float4 a0 = *(const float4*)ag;
        float4 a1 = *(const float4*)(ag + 4);
        short* asp = &As[arow * 32 + acol];
        asp[0] = f2bf(a0.x); asp[1] = f2bf(a0.y); asp[2] = f2bf(a0.z); asp[3] = f2bf(a0.w);
        asp[4] = f2bf(a1.x); asp[5] = f2bf(a1.y); asp[6] = f2bf(a1.z); asp[7] = f2bf(a1.w);
        // stage B tile transposed: Bt[n][k]
        const float* bg = B + (size_t)(k0 + bk) * N + n0 + bn;
        if (n0 + bn + 8 <= N) {
            float4 b0 = *(const float4*)bg;
            float4 b1 = *(const float4*)(bg + 4);
            float bv[8] = {b0.x, b0.y, b0.z, b0.w, b1.x, b1.y, b1.z, b1.w};
            #pragma unroll
            for (int i = 0; i < 8; i++) Bt[(bn + i) * 32 + bk] = f2bf(bv[i]);
        } else {
            #pragma unroll
            for (int i = 0; i < 8; i++) {
                float v = (n0 + bn + i < N) ? bg[i] : 0.0f;
                Bt[(bn + i) * 32 + bk] = f2bf(v);
            }
        }
        __syncthreads();
        // compute: wave handles rows [wave*16, wave*16+16), all 4 n-tiles
        bf16x8 af = *(const bf16x8*)&As[(wave * 16 + lm) * 32 + quad * 8];
        #pragma unroll
        for (int nt = 0; nt < 4; nt++) {
            bf16x8 bfv = *(const bf16x8*)&Bt[(nt * 16 + lm) * 32 + quad * 8];
            acc[nt] = __builtin_amdgcn_mfma_f32_16x16x32_bf16(af, bfv, acc[nt], 0, 0, 0);
        }
        __syncthreads();
    }
    // epilogue: D lane mapping col = lane&15, row = quad*4 + r
    #pragma unroll
    for (int nt = 0; nt < 4; nt++) {
        int col = n0 + nt * 16 + lm;
        if (col >= N) continue;
        float bb = bias ? bias[col] : 0.0f;
        #pragma unroll
        for (int r = 0; r < 4; r++) {
            int row = row0 + wave * 16 + quad * 4 + r;
            float v = acc[nt][r] + bb;
            size_t idx = (size_t)row * N + col;
            if (resid) v = resid[idx] + gamma[col] * v;
            C[idx] = v;
        }
    }
}

// ---------------- softmax(24) + bilinear sampling --------------------------
// one block (256 threads) per query row; thread t covers d = t&127, heads {t>>7, +2, +4}
__global__ __launch_bounds__(256) void sample_kernel(
        const float* __restrict__ offs, const float* __restrict__ awl,
        const float* __restrict__ refp, const float* __restrict__ value,
        float* __restrict__ out) {
    int row = blockIdx.x;             // b*NQ + q
    int b = row / NQ;
    int tid = threadIdx.x;
    __shared__ float swx[24], swy[24], slog[24], sexp[24];
    __shared__ int sx0[24], sy0[24];
    if (tid < 24) {
        int h = tid >> 2, p = tid & 3;
        float rx = refp[row * 2 + 0], ry = refp[row * 2 + 1];
        float ox = offs[row * 48 + h * 8 + p * 2 + 0];
        float oy = offs[row * 48 + h * 8 + p * 2 + 1];
        float lx = rx + ox * (1.0f / HW_DIM);
        float ly = ry + oy * (1.0f / HW_DIM);
        float x = lx * HW_DIM - 0.5f;
        float y = ly * HW_DIM - 0.5f;
        float fx = floorf(x), fy = floorf(y);
        sx0[tid] = (int)fx; sy0[tid] = (int)fy;
        swx[tid] = x - fx;  swy[tid] = y - fy;
        slog[tid] = awl[row * 24 + tid];
    }
    __syncthreads();
    if (tid < 24) {
        float m = slog[0];
        for (int i = 1; i < 24; i++) m = fmaxf(m, slog[i]);
        sexp[tid] = expf(slog[tid] - m);
    }
    __syncthreads();
    float ssum = 0.f;
    for (int i = 0; i < 24; i++) ssum += sexp[i];
    float inv = 1.0f / ssum;

    int d = tid & 127;
    int hbase = tid >> 7;
    const float* vb = value + (size_t)b * NV * DIM;
    float* orow = out + (size_t)row * DIM;
    for (int hh = 0; hh < 3; hh++) {
        int h = hbase + hh * 2;
        float acc = 0.0f;
        #pragma unroll
        for (int p = 0; p < 4; p++) {
            int idx = h * 4 + p;
            int x0 = sx0[idx], y0 = sy0[idx];
            float wx = swx[idx], wy = swy[idx];
            float aw = sexp[idx] * inv;
            int x1 = x0 + 1, y1 = y0 + 1;
            bool vx0 = (x0 >= 0) && (x0 < HW_DIM), vx1 = (x1 >= 0) && (x1 < HW_DIM);
            bool vy0 = (y0 >= 0) && (y0 < HW_DIM), vy1 = (y1 >= 0) && (y1 < HW_DIM);
            int col = h * HD + d;
            float v00 = (vx0 && vy0) ? vb[(size_t)(y0 * HW_DIM + x0) * DIM + col] : 0.0f;
            float v01 = (vx1 && vy0) ? vb[(size_t)(y0 * HW_DIM + x1) * DIM + col] : 0.0f;
            float v10 = (vx0 && vy1) ? vb[(size_t)(y1 * HW_DIM + x0) * DIM + col] : 0.0f;
            float v11 = (vx1 && vy1) ? vb[(size_t)(y1 * HW_DIM + x1) * DIM + col] : 0.0f;
            acc += aw * ((1.f - wy) * ((1.f - wx) * v00 + wx * v01)
                       +        wy  * ((1.f - wx) * v10 + wx * v11));
        }
        orow[h * HD + d] = acc;
    }
}

extern "C" void kernel_launch(void* const* d_in, const int* in_sizes, int n_in,
                              void* d_out, int out_size, void* d_ws, size_t ws_size,
                              hipStream_t stream) {
    const float* query = (const float*)d_in[0];
    const float* refp  = (const float*)d_in[1];
    const float* feat  = (const float*)d_in[2];
    // d_in[3] spatial_shapes, d_in[4] level_start_index: constants, unused
    const float* ln_w  = (const float*)d_in[5];
    const float* ln_b  = (const float*)d_in[6];
    const float* vp_w  = (const float*)d_in[7];
    const float* vp_b  = (const float*)d_in[8];
    const float* off_w = (const float*)d_in[9];
    const float* off_b = (const float*)d_in[10];
    const float* aw_w  = (const float*)d_in[11];
    const float* aw_b  = (const float*)d_in[12];
    const float* out_w = (const float*)d_in[13];
    const float* out_b = (const float*)d_in[14];
    const float* gamma = (const float*)d_in[15];

    float* ws    = (float*)d_ws;
    float* q_ws  = ws;                                   // 8192*768
    float* v_ws  = q_ws  + (size_t)M_TOTAL * DIM;        // 8192*768
    float* o_ws  = v_ws  + (size_t)M_TOTAL * DIM;        // 8192*48
    float* a_ws  = o_ws  + (size_t)M_TOTAL * 48;         // 8192*24
    float* s_ws  = a_ws  + (size_t)M_TOTAL * 24;         // 8192*768
    float* out_f = (float*)d_out;

    ln_kernel<<<M_TOTAL, 256, 0, stream>>>(query, ln_w, ln_b, q_ws);
    gemm_kernel<<<dim3(12, 128), 256, 0, stream>>>(feat, vp_w, vp_b, v_ws,
                                                   M_TOTAL, DIM, DIM, nullptr, nullptr);
    gemm_kernel<<<dim3(1, 128), 256, 0, stream>>>(q_ws, off_w, off_b, o_ws,
                                                  M_TOTAL, 48, DIM, nullptr, nullptr);
    gemm_kernel<<<dim3(1, 128), 256, 0, stream>>>(q_ws, aw_w, aw_b, a_ws,
                                                  M_TOTAL, 24, DIM, nullptr, nullptr);
    sample_kernel<<<M_TOTAL, 256, 0, stream>>>(o_ws, a_ws, refp, v_ws, s_ws);
    gemm_kernel<<<dim3(12, 128), 256, 0, stream>>>(s_ws, out_w, out_b, out_f,
                                                   M_TOTAL, DIM, DIM, query, gamma);
}

// Round 2
// 269.006 us; speedup vs baseline: 1.2590x; 1.2590x over previous
//
#include <hip/hip_runtime.h>
#include <hip/hip_bf16.h>
#include <math.h>

#define BSZ 2
#define NQ 4096
#define DIM 768
#define HEADS 6
#define POINTS 4
#define HD 128
#define HW_DIM 64
#define NV (HW_DIM*HW_DIM)
#define M_TOTAL (BSZ*NQ)   // 8192
#define KDIM 768

typedef __attribute__((ext_vector_type(8))) short bf16x8;
typedef __attribute__((ext_vector_type(4))) float f32x4;
typedef unsigned int u32;
typedef unsigned short u16;

__device__ inline u16 f2bf(float f) {
    union { float f; u32 u; } v; v.f = f;
    u32 r = v.u + 0x7fffu + ((v.u >> 16) & 1u);
    return (u16)(r >> 16);
}

#define GLD16(g, l) __builtin_amdgcn_global_load_lds( \
    (const __attribute__((address_space(1))) u32*)(g), \
    (__attribute__((address_space(3))) u32*)(l), 16, 0, 0)

// ---------------- LayerNorm -> bf16 output --------------------------------
__global__ __launch_bounds__(256) void ln_bf_kernel(const float* __restrict__ x,
        const float* __restrict__ w, const float* __restrict__ b,
        u16* __restrict__ q) {
    int row = blockIdx.x;
    int tid = threadIdx.x;
    const float* xr = x + (size_t)row * DIM;
    float v0 = xr[tid], v1 = xr[tid + 256], v2 = xr[tid + 512];
    float s  = v0 + v1 + v2;
    float ss = v0*v0 + v1*v1 + v2*v2;
    __shared__ float red[256], red2[256];
    red[tid] = s; red2[tid] = ss;
    __syncthreads();
    for (int st = 128; st > 0; st >>= 1) {
        if (tid < st) { red[tid] += red[tid + st]; red2[tid] += red2[tid + st]; }
        __syncthreads();
    }
    float mean = red[0] * (1.0f / DIM);
    float var  = red2[0] * (1.0f / DIM) - mean * mean;
    float rstd = rsqrtf(var + 1e-6f);
    u16* qr = q + (size_t)row * DIM;
    qr[tid]       = f2bf((v0 - mean) * rstd * w[tid]       + b[tid]);
    qr[tid + 256] = f2bf((v1 - mean) * rstd * w[tid + 256] + b[tid + 256]);
    qr[tid + 512] = f2bf((v2 - mean) * rstd * w[tid + 512] + b[tid + 512]);
}

// ---------------- fp32 -> bf16 convert (contiguous) ------------------------
__global__ __launch_bounds__(256) void cvt_bf16(const float* __restrict__ src,
        u16* __restrict__ dst, int n) {
    int i = (blockIdx.x * 256 + threadIdx.x) * 4;
    if (i >= n) return;
    float4 v = *(const float4*)(src + i);
    ushort4 o;
    o.x = f2bf(v.x); o.y = f2bf(v.y); o.z = f2bf(v.z); o.w = f2bf(v.w);
    *(ushort4*)(dst + i) = o;
}

// ---------------- transpose + convert: src[k][n] -> dst[rowOff+n][k] -------
// writes zeros for n >= N within the 32-wide tile (used for padding)
__global__ __launch_bounds__(256) void transpose_cvt(const float* __restrict__ src,
        u16* __restrict__ dst, int K, int N, int rowOff, int dstStride) {
    __shared__ float tile[32][33];
    int n0 = blockIdx.x * 32, k0 = blockIdx.y * 32;
    int tx = threadIdx.x & 31, ty = threadIdx.x >> 5;  // ty: 0..7
    #pragma unroll
    for (int r = 0; r < 4; r++) {
        int k = k0 + ty + r * 8, n = n0 + tx;
        float v = 0.0f;
        if (k < K && n < N) v = src[(size_t)k * N + n];
        tile[ty + r * 8][tx] = v;
    }
    __syncthreads();
    #pragma unroll
    for (int r = 0; r < 4; r++) {
        int nn = ty + r * 8, kk = tx;
        dst[(size_t)(rowOff + n0 + nn) * dstStride + k0 + kk] = f2bf(tile[kk][nn]);
    }
}

// ---------------- big GEMM: A[M][K]bf16 * Bt[N][K]bf16, 128x128 tile -------
// out: bf16 (storeBF16) or fp32 with optional resid + gamma epilogue
__global__ __launch_bounds__(256, 2) void gemm_bt(
        const u16* __restrict__ A, const u16* __restrict__ Bt,
        const float* __restrict__ bias, void* __restrict__ Cout,
        int M, int N, int K, int storeBF16,
        const float* __restrict__ resid, const float* __restrict__ gamma) {
    __shared__ u16 As[128 * 32];
    __shared__ u16 Bs[128 * 32];
    int tid = threadIdx.x;
    int wave = tid >> 6, lane = tid & 63;
    int lm = lane & 15, quad = lane >> 4;
    int n0 = blockIdx.x * 128, m0 = blockIdx.y * 128;
    int wr = wave & 1, wc = wave >> 1;
    f32x4 acc[4][4];
    #pragma unroll
    for (int i = 0; i < 4; i++)
        #pragma unroll
        for (int j = 0; j < 4; j++) acc[i][j] = (f32x4){0.f, 0.f, 0.f, 0.f};

    int lrow = lane >> 2;          // 0..15
    int lcol = (lane & 3) * 8;     // shorts
    const u16* Ab = A + (size_t)m0 * K;
    const u16* Bb = Bt + (size_t)n0 * K;

    for (int k0 = 0; k0 < K; k0 += 32) {
        #pragma unroll
        for (int c = 0; c < 2; c++) {
            int rbase = wave * 32 + c * 16;
            GLD16(Ab + (size_t)(rbase + lrow) * K + k0 + lcol, &As[rbase * 32]);
            GLD16(Bb + (size_t)(rbase + lrow) * K + k0 + lcol, &Bs[rbase * 32]);
        }
        __syncthreads();
        const u16* Aw = &As[wr * 64 * 32];
        const u16* Bw = &Bs[wc * 64 * 32];
        bf16x8 af[4], bfv[4];
        #pragma unroll
        for (int i = 0; i < 4; i++) af[i]  = *(const bf16x8*)&Aw[(i * 16 + lm) * 32 + quad * 8];
        #pragma unroll
        for (int i = 0; i < 4; i++) bfv[i] = *(const bf16x8*)&Bw[(i * 16 + lm) * 32 + quad * 8];
        #pragma unroll
        for (int am = 0; am < 4; am++)
            #pragma unroll
            for (int bn = 0; bn < 4; bn++)
                acc[am][bn] = __builtin_amdgcn_mfma_f32_16x16x32_bf16(af[am], bfv[bn], acc[am][bn], 0, 0, 0);
        __syncthreads();
    }

    #pragma unroll
    for (int bn = 0; bn < 4; bn++) {
        int col = n0 + wc * 64 + bn * 16 + lm;
        float bb = bias[col];
        #pragma unroll
        for (int am = 0; am < 4; am++) {
            #pragma unroll
            for (int r = 0; r < 4; r++) {
                int row = m0 + wr * 64 + am * 16 + quad * 4 + r;
                size_t idx = (size_t)row * N + col;
                float v = acc[am][bn][r] + bb;
                if (storeBF16) {
                    ((u16*)Cout)[idx] = f2bf(v);
                } else {
                    float o = resid ? resid[idx] + gamma[col] * v : v;
                    ((float*)Cout)[idx] = o;
                }
            }
        }
    }
}

// ---------------- small GEMM: q[M][768] * Wt[80][768] -> oa[M][80] fp32 ----
__global__ __launch_bounds__(256, 2) void gemm_small(
        const u16* __restrict__ A, const u16* __restrict__ Bt,
        const float* __restrict__ b0, const float* __restrict__ b1,
        float* __restrict__ C, int M, int K) {
    __shared__ u16 As[64 * 32];
    __shared__ u16 Bs[80 * 32];
    int tid = threadIdx.x, wave = tid >> 6, lane = tid & 63;
    int lm = lane & 15, quad = lane >> 4;
    int m0 = blockIdx.x * 64;
    f32x4 acc[5];
    #pragma unroll
    for (int i = 0; i < 5; i++) acc[i] = (f32x4){0.f, 0.f, 0.f, 0.f};
    int lrow = lane >> 2, lcol = (lane & 3) * 8;

    for (int k0 = 0; k0 < K; k0 += 32) {
        for (int c = wave; c < 9; c += 4) {
            if (c < 4) {
                GLD16(A + (size_t)(m0 + c * 16 + lrow) * K + k0 + lcol, &As[c * 16 * 32]);
            } else {
                GLD16(Bt + (size_t)((c - 4) * 16 + lrow) * K + k0 + lcol, &Bs[(c - 4) * 16 * 32]);
            }
        }
        __syncthreads();
        bf16x8 af = *(const bf16x8*)&As[(wave * 16 + lm) * 32 + quad * 8];
        #pragma unroll
        for (int bn = 0; bn < 5; bn++) {
            bf16x8 bv = *(const bf16x8*)&Bs[(bn * 16 + lm) * 32 + quad * 8];
            acc[bn] = __builtin_amdgcn_mfma_f32_16x16x32_bf16(af, bv, acc[bn], 0, 0, 0);
        }
        __syncthreads();
    }
    #pragma unroll
    for (int bn = 0; bn < 5; bn++) {
        int col = bn * 16 + lm;
        float bb = (col < 48) ? b0[col] : ((col < 72) ? b1[col - 48] : 0.0f);
        #pragma unroll
        for (int r = 0; r < 4; r++) {
            int row = m0 + wave * 16 + quad * 4 + r;
            C[(size_t)row * 80 + col] = acc[bn][r] + bb;
        }
    }
}

// ---------------- softmax(24) + bilinear sampling, bf16 value --------------
// block 384 = 6 waves, wave = head; lane covers 2 consecutive d's
__global__ __launch_bounds__(384) void sample_kernel(
        const float* __restrict__ oa, const float* __restrict__ refp,
        const u16* __restrict__ v, u16* __restrict__ out) {
    int row = blockIdx.x;
    int b = row >> 12;                 // NQ = 4096
    int tid = threadIdx.x;
    __shared__ float s_wx[24], s_wy[24], s_l[24], s_e[24];
    __shared__ int s_x0[24], s_y0[24];
    const float* oar = oa + (size_t)row * 80;
    if (tid < 24) {
        int h = tid >> 2, p = tid & 3;
        float rx = refp[row * 2 + 0], ry = refp[row * 2 + 1];
        float x = (rx + oar[h * 8 + p * 2 + 0] * (1.0f / HW_DIM)) * HW_DIM - 0.5f;
        float y = (ry + oar[h * 8 + p * 2 + 1] * (1.0f / HW_DIM)) * HW_DIM - 0.5f;
        float fx = floorf(x), fy = floorf(y);
        s_x0[tid] = (int)fx; s_y0[tid] = (int)fy;
        s_wx[tid] = x - fx;  s_wy[tid] = y - fy;
        s_l[tid] = oar[48 + tid];
    }
    __syncthreads();
    if (tid < 24) {
        float m = s_l[0];
        #pragma unroll
        for (int i = 1; i < 24; i++) m = fmaxf(m, s_l[i]);
        s_e[tid] = expf(s_l[tid] - m);
    }
    __syncthreads();
    float ssum = 0.0f;
    #pragma unroll
    for (int i = 0; i < 24; i++) ssum += s_e[i];
    float inv = 1.0f / ssum;

    int h = tid >> 6;
    int d2 = (tid & 63) * 2;
    const u16* vb = v + (size_t)b * NV * DIM + h * HD + d2;
    float a0 = 0.0f, a1 = 0.0f;
    #pragma unroll
    for (int p = 0; p < 4; p++) {
        int idx = h * 4 + p;
        int x0 = s_x0[idx], y0 = s_y0[idx];
        float wx = s_wx[idx], wy = s_wy[idx];
        float aw = s_e[idx] * inv;
        float w00 = aw * (1.f - wy) * (1.f - wx);
        float w01 = aw * (1.f - wy) * wx;
        float w10 = aw * wy * (1.f - wx);
        float w11 = aw * wy * wx;
        int x1 = x0 + 1, y1 = y0 + 1;
        bool vx0 = (x0 >= 0) & (x0 < HW_DIM), vx1 = (x1 >= 0) & (x1 < HW_DIM);
        bool vy0 = (y0 >= 0) & (y0 < HW_DIM), vy1 = (y1 >= 0) & (y1 < HW_DIM);
        if (vy0 & vx0) {
            u32 u = *(const u32*)(vb + (size_t)(y0 * HW_DIM + x0) * DIM);
            a0 += w00 * __uint_as_float(u << 16);
            a1 += w00 * __uint_as_float(u & 0xffff0000u);
        }
        if (vy0 & vx1) {
            u32 u = *(const u32*)(vb + (size_t)(y0 * HW_DIM + x1) * DIM);
            a0 += w01 * __uint_as_float(u << 16);
            a1 += w01 * __uint_as_float(u & 0xffff0000u);
        }
        if (vy1 & vx0) {
            u32 u = *(const u32*)(vb + (size_t)(y1 * HW_DIM + x0) * DIM);
            a0 += w10 * __uint_as_float(u << 16);
            a1 += w10 * __uint_as_float(u & 0xffff0000u);
        }
        if (vy1 & vx1) {
            u32 u = *(const u32*)(vb + (size_t)(y1 * HW_DIM + x1) * DIM);
            a0 += w11 * __uint_as_float(u << 16);
            a1 += w11 * __uint_as_float(u & 0xffff0000u);
        }
    }
    u32 pack = (u32)f2bf(a0) | ((u32)f2bf(a1) << 16);
    *(u32*)&out[(size_t)row * DIM + h * HD + d2] = pack;
}

extern "C" void kernel_launch(void* const* d_in, const int* in_sizes, int n_in,
                              void* d_out, int out_size, void* d_ws, size_t ws_size,
                              hipStream_t stream) {
    const float* query = (const float*)d_in[0];
    const float* refp  = (const float*)d_in[1];
    const float* feat  = (const float*)d_in[2];
    const float* ln_w  = (const float*)d_in[5];
    const float* ln_b  = (const float*)d_in[6];
    const float* vp_w  = (const float*)d_in[7];
    const float* vp_b  = (const float*)d_in[8];
    const float* off_w = (const float*)d_in[9];
    const float* off_b = (const float*)d_in[10];
    const float* aw_w  = (const float*)d_in[11];
    const float* aw_b  = (const float*)d_in[12];
    const float* out_w = (const float*)d_in[13];
    const float* out_b = (const float*)d_in[14];
    const float* gamma = (const float*)d_in[15];

    const size_t MD = (size_t)M_TOTAL * DIM;      // 6291456
    char* ws = (char*)d_ws;
    u16* q_bf    = (u16*)ws;                 ws += MD * 2;
    u16* feat_bf = (u16*)ws;                 ws += MD * 2;
    u16* v_bf    = (u16*)ws;                 ws += MD * 2;
    u16* s_bf    = (u16*)ws;                 ws += MD * 2;
    u16* vp_wt   = (u16*)ws;                 ws += (size_t)DIM * DIM * 2;
    u16* out_wt  = (u16*)ws;                 ws += (size_t)DIM * DIM * 2;
    u16* oaw_wt  = (u16*)ws;                 ws += (size_t)80 * KDIM * 2;
    float* oa    = (float*)ws;               ws += (size_t)M_TOTAL * 80 * 4;
    float* out_f = (float*)d_out;

    // prep passes
    ln_bf_kernel<<<M_TOTAL, 256, 0, stream>>>(query, ln_w, ln_b, q_bf);
    cvt_bf16<<<(int)(MD / 1024), 256, 0, stream>>>(feat, feat_bf, (int)MD);
    transpose_cvt<<<dim3(24, 24), 256, 0, stream>>>(vp_w,  vp_wt,  KDIM, DIM, 0, KDIM);
    transpose_cvt<<<dim3(24, 24), 256, 0, stream>>>(out_w, out_wt, KDIM, DIM, 0, KDIM);
    transpose_cvt<<<dim3(2, 24),  256, 0, stream>>>(off_w, oaw_wt, KDIM, 48, 0, KDIM);
    transpose_cvt<<<dim3(1, 24),  256, 0, stream>>>(aw_w,  oaw_wt, KDIM, 24, 48, KDIM); // rows 48..79, zero-pads 72..79

    // value = feat @ vp_w + vp_b   (bf16 out)
    gemm_bt<<<dim3(6, 64), 256, 0, stream>>>(feat_bf, vp_wt, vp_b, v_bf,
                                             M_TOTAL, DIM, KDIM, 1, nullptr, nullptr);
    // offsets + aw logits fused
    gemm_small<<<128, 256, 0, stream>>>(q_bf, oaw_wt, off_b, aw_b, oa, M_TOTAL, KDIM);
    // sampling
    sample_kernel<<<M_TOTAL, 384, 0, stream>>>(oa, refp, v_bf, s_bf);
    // out = query + gamma * (s @ out_w + out_b)
    gemm_bt<<<dim3(6, 64), 256, 0, stream>>>(s_bf, out_wt, out_b, out_f,
                                             M_TOTAL, DIM, KDIM, 0, query, gamma);
}

// Round 3
// 233.238 us; speedup vs baseline: 1.4521x; 1.1534x over previous
//
#include <hip/hip_runtime.h>
#include <hip/hip_bf16.h>
#include <math.h>

#define BSZ 2
#define NQ 4096
#define DIM 768
#define HEADS 6
#define POINTS 4
#define HD 128
#define HW_DIM 64
#define NV (HW_DIM*HW_DIM)
#define M_TOTAL (BSZ*NQ)   // 8192
#define KDIM 768
#define KSPLIT 4
#define KPART (KDIM/KSPLIT)  // 192

typedef __attribute__((ext_vector_type(8))) short bf16x8;
typedef __attribute__((ext_vector_type(4))) float f32x4;
typedef unsigned int u32;
typedef unsigned short u16;

__device__ inline u16 f2bf(float f) {
    union { float f; u32 u; } v; v.f = f;
    u32 r = v.u + 0x7fffu + ((v.u >> 16) & 1u);
    return (u16)(r >> 16);
}

#define GLD16(g, l) __builtin_amdgcn_global_load_lds( \
    (const __attribute__((address_space(1))) u32*)(g), \
    (__attribute__((address_space(3))) u32*)(l), 16, 0, 0)

// ---------------- LayerNorm -> bf16 output --------------------------------
__global__ __launch_bounds__(256) void ln_bf_kernel(const float* __restrict__ x,
        const float* __restrict__ w, const float* __restrict__ b,
        u16* __restrict__ q) {
    int row = blockIdx.x;
    int tid = threadIdx.x;
    const float* xr = x + (size_t)row * DIM;
    float v0 = xr[tid], v1 = xr[tid + 256], v2 = xr[tid + 512];
    float s  = v0 + v1 + v2;
    float ss = v0*v0 + v1*v1 + v2*v2;
    __shared__ float red[256], red2[256];
    red[tid] = s; red2[tid] = ss;
    __syncthreads();
    for (int st = 128; st > 0; st >>= 1) {
        if (tid < st) { red[tid] += red[tid + st]; red2[tid] += red2[tid + st]; }
        __syncthreads();
    }
    float mean = red[0] * (1.0f / DIM);
    float var  = red2[0] * (1.0f / DIM) - mean * mean;
    float rstd = rsqrtf(var + 1e-6f);
    u16* qr = q + (size_t)row * DIM;
    qr[tid]       = f2bf((v0 - mean) * rstd * w[tid]       + b[tid]);
    qr[tid + 256] = f2bf((v1 - mean) * rstd * w[tid + 256] + b[tid + 256]);
    qr[tid + 512] = f2bf((v2 - mean) * rstd * w[tid + 512] + b[tid + 512]);
}

// ---------------- fp32 -> bf16 convert (contiguous) ------------------------
__global__ __launch_bounds__(256) void cvt_bf16(const float* __restrict__ src,
        u16* __restrict__ dst, int n) {
    int i = (blockIdx.x * 256 + threadIdx.x) * 4;
    if (i >= n) return;
    float4 v = *(const float4*)(src + i);
    ushort4 o;
    o.x = f2bf(v.x); o.y = f2bf(v.y); o.z = f2bf(v.z); o.w = f2bf(v.w);
    *(ushort4*)(dst + i) = o;
}

// ---------------- transpose + convert: src[k][n] -> dst[rowOff+n][k] -------
__global__ __launch_bounds__(256) void transpose_cvt(const float* __restrict__ src,
        u16* __restrict__ dst, int K, int N, int rowOff, int dstStride) {
    __shared__ float tile[32][33];
    int n0 = blockIdx.x * 32, k0 = blockIdx.y * 32;
    int tx = threadIdx.x & 31, ty = threadIdx.x >> 5;  // ty: 0..7
    #pragma unroll
    for (int r = 0; r < 4; r++) {
        int k = k0 + ty + r * 8, n = n0 + tx;
        float v = 0.0f;
        if (k < K && n < N) v = src[(size_t)k * N + n];
        tile[ty + r * 8][tx] = v;
    }
    __syncthreads();
    #pragma unroll
    for (int r = 0; r < 4; r++) {
        int nn = ty + r * 8, kk = tx;
        dst[(size_t)(rowOff + n0 + nn) * dstStride + k0 + kk] = f2bf(tile[kk][nn]);
    }
}

// ---------------- big GEMM: A[M][K]bf16 * Bt[N][K]bf16, 128x128 tile -------
__global__ __launch_bounds__(256, 2) void gemm_bt(
        const u16* __restrict__ A, const u16* __restrict__ Bt,
        const float* __restrict__ bias, void* __restrict__ Cout,
        int M, int N, int K, int storeBF16,
        const float* __restrict__ resid, const float* __restrict__ gamma) {
    __shared__ u16 As[128 * 32];
    __shared__ u16 Bs[128 * 32];
    int tid = threadIdx.x;
    int wave = tid >> 6, lane = tid & 63;
    int lm = lane & 15, quad = lane >> 4;
    int n0 = blockIdx.x * 128, m0 = blockIdx.y * 128;
    int wr = wave & 1, wc = wave >> 1;
    f32x4 acc[4][4];
    #pragma unroll
    for (int i = 0; i < 4; i++)
        #pragma unroll
        for (int j = 0; j < 4; j++) acc[i][j] = (f32x4){0.f, 0.f, 0.f, 0.f};

    int lrow = lane >> 2;          // 0..15
    int lcol = (lane & 3) * 8;     // shorts
    const u16* Ab = A + (size_t)m0 * K;
    const u16* Bb = Bt + (size_t)n0 * K;

    for (int k0 = 0; k0 < K; k0 += 32) {
        #pragma unroll
        for (int c = 0; c < 2; c++) {
            int rbase = wave * 32 + c * 16;
            GLD16(Ab + (size_t)(rbase + lrow) * K + k0 + lcol, &As[rbase * 32]);
            GLD16(Bb + (size_t)(rbase + lrow) * K + k0 + lcol, &Bs[rbase * 32]);
        }
        __syncthreads();
        const u16* Aw = &As[wr * 64 * 32];
        const u16* Bw = &Bs[wc * 64 * 32];
        bf16x8 af[4], bfv[4];
        #pragma unroll
        for (int i = 0; i < 4; i++) af[i]  = *(const bf16x8*)&Aw[(i * 16 + lm) * 32 + quad * 8];
        #pragma unroll
        for (int i = 0; i < 4; i++) bfv[i] = *(const bf16x8*)&Bw[(i * 16 + lm) * 32 + quad * 8];
        #pragma unroll
        for (int am = 0; am < 4; am++)
            #pragma unroll
            for (int bn = 0; bn < 4; bn++)
                acc[am][bn] = __builtin_amdgcn_mfma_f32_16x16x32_bf16(af[am], bfv[bn], acc[am][bn], 0, 0, 0);
        __syncthreads();
    }

    #pragma unroll
    for (int bn = 0; bn < 4; bn++) {
        int col = n0 + wc * 64 + bn * 16 + lm;
        float bb = bias[col];
        #pragma unroll
        for (int am = 0; am < 4; am++) {
            #pragma unroll
            for (int r = 0; r < 4; r++) {
                int row = m0 + wr * 64 + am * 16 + quad * 4 + r;
                size_t idx = (size_t)row * N + col;
                float v = acc[am][bn][r] + bb;
                if (storeBF16) {
                    ((u16*)Cout)[idx] = f2bf(v);
                } else {
                    float o = resid ? resid[idx] + gamma[col] * v : v;
                    ((float*)Cout)[idx] = o;
                }
            }
        }
    }
}

// ---------------- small GEMM, K-split: q[M][Kpart] * Wt[80][Kpart] ---------
// blockIdx.x = m-block (64 rows), blockIdx.y = k-part; writes oa + part*M*80
__global__ __launch_bounds__(256, 2) void gemm_small(
        const u16* __restrict__ A, const u16* __restrict__ Bt,
        const float* __restrict__ b0, const float* __restrict__ b1,
        float* __restrict__ C, int M, int K) {
    __shared__ u16 As[64 * 32];
    __shared__ u16 Bs[80 * 32];
    int tid = threadIdx.x, wave = tid >> 6, lane = tid & 63;
    int lm = lane & 15, quad = lane >> 4;
    int m0 = blockIdx.x * 64;
    int part = blockIdx.y;
    int kbase = part * KPART;
    f32x4 acc[5];
    #pragma unroll
    for (int i = 0; i < 5; i++) acc[i] = (f32x4){0.f, 0.f, 0.f, 0.f};
    int lrow = lane >> 2, lcol = (lane & 3) * 8;

    for (int k0 = kbase; k0 < kbase + KPART; k0 += 32) {
        for (int c = wave; c < 9; c += 4) {
            if (c < 4) {
                GLD16(A + (size_t)(m0 + c * 16 + lrow) * K + k0 + lcol, &As[c * 16 * 32]);
            } else {
                GLD16(Bt + (size_t)((c - 4) * 16 + lrow) * K + k0 + lcol, &Bs[(c - 4) * 16 * 32]);
            }
        }
        __syncthreads();
        bf16x8 af = *(const bf16x8*)&As[(wave * 16 + lm) * 32 + quad * 8];
        #pragma unroll
        for (int bn = 0; bn < 5; bn++) {
            bf16x8 bv = *(const bf16x8*)&Bs[(bn * 16 + lm) * 32 + quad * 8];
            acc[bn] = __builtin_amdgcn_mfma_f32_16x16x32_bf16(af, bv, acc[bn], 0, 0, 0);
        }
        __syncthreads();
    }
    float* Cp = C + (size_t)part * M_TOTAL * 80;
    #pragma unroll
    for (int bn = 0; bn < 5; bn++) {
        int col = bn * 16 + lm;
        float bb = 0.0f;
        if (part == 0) bb = (col < 48) ? b0[col] : ((col < 72) ? b1[col - 48] : 0.0f);
        #pragma unroll
        for (int r = 0; r < 4; r++) {
            int row = m0 + wave * 16 + quad * 4 + r;
            Cp[(size_t)row * 80 + col] = acc[bn][r] + bb;
        }
    }
}

// ---------------- softmax(24) + bilinear sampling, predicated loads --------
// block 384 = 6 waves, wave = head; lane covers 2 consecutive d's
__global__ __launch_bounds__(384) void sample_kernel(
        const float* __restrict__ oa, const float* __restrict__ refp,
        const u16* __restrict__ v, u16* __restrict__ out) {
    int row = blockIdx.x;
    int b = row >> 12;                 // NQ = 4096
    int tid = threadIdx.x;
    __shared__ float s_w[4][24];       // validity-premultiplied corner weights
    __shared__ int   s_o[4][24];       // clamped element offsets (incl. batch base)
    __shared__ float s_e[24];
    if (tid < 24) {
        int h = tid >> 2, p = tid & 3;
        float ox = 0.f, oy = 0.f, lg = 0.f;
        #pragma unroll
        for (int part = 0; part < KSPLIT; part++) {
            const float* pp = oa + (size_t)part * M_TOTAL * 80 + (size_t)row * 80;
            ox += pp[h * 8 + p * 2 + 0];
            oy += pp[h * 8 + p * 2 + 1];
            lg += pp[48 + tid];
        }
        float rx = refp[row * 2 + 0], ry = refp[row * 2 + 1];
        float x = (rx + ox * (1.0f / HW_DIM)) * HW_DIM - 0.5f;
        float y = (ry + oy * (1.0f / HW_DIM)) * HW_DIM - 0.5f;
        float fx = floorf(x), fy = floorf(y);
        int x0 = (int)fx, y0 = (int)fy;
        int x1 = x0 + 1, y1 = y0 + 1;
        float wx = x - fx, wy = y - fy;
        float vx0 = (x0 >= 0 && x0 < HW_DIM) ? 1.f : 0.f;
        float vx1 = (x1 >= 0 && x1 < HW_DIM) ? 1.f : 0.f;
        float vy0 = (y0 >= 0 && y0 < HW_DIM) ? 1.f : 0.f;
        float vy1 = (y1 >= 0 && y1 < HW_DIM) ? 1.f : 0.f;
        int xc0 = min(max(x0, 0), HW_DIM - 1), xc1 = min(max(x1, 0), HW_DIM - 1);
        int yc0 = min(max(y0, 0), HW_DIM - 1), yc1 = min(max(y1, 0), HW_DIM - 1);
        int base = b * NV * DIM;
        s_o[0][tid] = base + (yc0 * HW_DIM + xc0) * DIM;
        s_o[1][tid] = base + (yc0 * HW_DIM + xc1) * DIM;
        s_o[2][tid] = base + (yc1 * HW_DIM + xc0) * DIM;
        s_o[3][tid] = base + (yc1 * HW_DIM + xc1) * DIM;
        s_w[0][tid] = (1.f - wy) * (1.f - wx) * vy0 * vx0;
        s_w[1][tid] = (1.f - wy) * wx * vy0 * vx1;
        s_w[2][tid] = wy * (1.f - wx) * vy1 * vx0;
        s_w[3][tid] = wy * wx * vy1 * vx1;
        // softmax exp within wave 0 (intra-wave LDS ordering, no barrier)
        s_e[tid] = lg;
        float m = s_e[0];
        #pragma unroll
        for (int i = 1; i < 24; i++) m = fmaxf(m, s_e[i]);
        s_e[tid] = expf(lg - m);
    }
    __syncthreads();
    float ssum = 0.0f;
    #pragma unroll
    for (int i = 0; i < 24; i++) ssum += s_e[i];
    float inv = 1.0f / ssum;

    int h = tid >> 6;
    int d2 = (tid & 63) * 2;
    const u16* vb = v + h * HD + d2;
    float a0 = 0.0f, a1 = 0.0f;
    #pragma unroll
    for (int p = 0; p < 4; p++) {
        int idx = h * 4 + p;
        float aw = s_e[idx] * inv;
        #pragma unroll
        for (int c = 0; c < 4; c++) {
            u32 u = *(const u32*)(vb + s_o[c][idx]);
            float w = aw * s_w[c][idx];
            a0 += w * __uint_as_float(u << 16);
            a1 += w * __uint_as_float(u & 0xffff0000u);
        }
    }
    u32 pack = (u32)f2bf(a0) | ((u32)f2bf(a1) << 16);
    *(u32*)&out[(size_t)row * DIM + h * HD + d2] = pack;
}

extern "C" void kernel_launch(void* const* d_in, const int* in_sizes, int n_in,
                              void* d_out, int out_size, void* d_ws, size_t ws_size,
                              hipStream_t stream) {
    const float* query = (const float*)d_in[0];
    const float* refp  = (const float*)d_in[1];
    const float* feat  = (const float*)d_in[2];
    const float* ln_w  = (const float*)d_in[5];
    const float* ln_b  = (const float*)d_in[6];
    const float* vp_w  = (const float*)d_in[7];
    const float* vp_b  = (const float*)d_in[8];
    const float* off_w = (const float*)d_in[9];
    const float* off_b = (const float*)d_in[10];
    const float* aw_w  = (const float*)d_in[11];
    const float* aw_b  = (const float*)d_in[12];
    const float* out_w = (const float*)d_in[13];
    const float* out_b = (const float*)d_in[14];
    const float* gamma = (const float*)d_in[15];

    const size_t MD = (size_t)M_TOTAL * DIM;      // 6291456
    char* ws = (char*)d_ws;
    u16* q_bf    = (u16*)ws;                 ws += MD * 2;
    u16* feat_bf = (u16*)ws;                 ws += MD * 2;
    u16* v_bf    = (u16*)ws;                 ws += MD * 2;
    u16* s_bf    = (u16*)ws;                 ws += MD * 2;
    u16* vp_wt   = (u16*)ws;                 ws += (size_t)DIM * DIM * 2;
    u16* out_wt  = (u16*)ws;                 ws += (size_t)DIM * DIM * 2;
    u16* oaw_wt  = (u16*)ws;                 ws += (size_t)80 * KDIM * 2;
    float* oa    = (float*)ws;               ws += (size_t)KSPLIT * M_TOTAL * 80 * 4;
    float* out_f = (float*)d_out;

    // prep passes
    ln_bf_kernel<<<M_TOTAL, 256, 0, stream>>>(query, ln_w, ln_b, q_bf);
    cvt_bf16<<<(int)(MD / 1024), 256, 0, stream>>>(feat, feat_bf, (int)MD);
    transpose_cvt<<<dim3(24, 24), 256, 0, stream>>>(vp_w,  vp_wt,  KDIM, DIM, 0, KDIM);
    transpose_cvt<<<dim3(24, 24), 256, 0, stream>>>(out_w, out_wt, KDIM, DIM, 0, KDIM);
    transpose_cvt<<<dim3(2, 24),  256, 0, stream>>>(off_w, oaw_wt, KDIM, 48, 0, KDIM);
    transpose_cvt<<<dim3(1, 24),  256, 0, stream>>>(aw_w,  oaw_wt, KDIM, 24, 48, KDIM);

    // value = feat @ vp_w + vp_b   (bf16 out)
    gemm_bt<<<dim3(6, 64), 256, 0, stream>>>(feat_bf, vp_wt, vp_b, v_bf,
                                             M_TOTAL, DIM, KDIM, 1, nullptr, nullptr);
    // offsets + aw logits fused, K split 4 ways
    gemm_small<<<dim3(128, KSPLIT), 256, 0, stream>>>(q_bf, oaw_wt, off_b, aw_b, oa, M_TOTAL, KDIM);
    // sampling
    sample_kernel<<<M_TOTAL, 384, 0, stream>>>(oa, refp, v_bf, s_bf);
    // out = query + gamma * (s @ out_w + out_b)
    gemm_bt<<<dim3(6, 64), 256, 0, stream>>>(s_bf, out_wt, out_b, out_f,
                                             M_TOTAL, DIM, KDIM, 0, query, gamma);
}

// Round 4
// 195.528 us; speedup vs baseline: 1.7321x; 1.1929x over previous
//
#include <hip/hip_runtime.h>
#include <hip/hip_bf16.h>
#include <math.h>

#define BSZ 2
#define NQ 4096
#define DIM 768
#define HEADS 6
#define POINTS 4
#define HD 128
#define HW_DIM 64
#define NV (HW_DIM*HW_DIM)
#define M_TOTAL (BSZ*NQ)   // 8192
#define KDIM 768
#define KSPLIT 4
#define KPART (KDIM/KSPLIT)  // 192

#define BM 64
#define BN 128
#define BKK 64
#define NBLK_M (M_TOTAL/BM)   // 128
#define NBLK_N (DIM/BN)       // 6
#define GEMM_GRID (NBLK_M*NBLK_N) // 768

typedef __attribute__((ext_vector_type(8))) short bf16x8;
typedef __attribute__((ext_vector_type(4))) float f32x4;
typedef unsigned int u32;
typedef unsigned short u16;

__device__ inline u16 f2bf(float f) {
    union { float f; u32 u; } v; v.f = f;
    u32 r = v.u + 0x7fffu + ((v.u >> 16) & 1u);
    return (u16)(r >> 16);
}

#define GLD16(g, l) __builtin_amdgcn_global_load_lds( \
    (const __attribute__((address_space(1))) u32*)(g), \
    (__attribute__((address_space(3))) u32*)(l), 16, 0, 0)

// ---------------- LayerNorm -> bf16 + fused feat fp32->bf16 ----------------
__global__ __launch_bounds__(256) void ln_bf_kernel(const float* __restrict__ x,
        const float* __restrict__ w, const float* __restrict__ b,
        u16* __restrict__ q, const float* __restrict__ feat,
        u16* __restrict__ feat_bf) {
    int row = blockIdx.x;
    int tid = threadIdx.x;
    const float* xr = x + (size_t)row * DIM;
    float v0 = xr[tid], v1 = xr[tid + 256], v2 = xr[tid + 512];
    // fused feat conversion (same row)
    const float* fr = feat + (size_t)row * DIM;
    u16* fb = feat_bf + (size_t)row * DIM;
    fb[tid]       = f2bf(fr[tid]);
    fb[tid + 256] = f2bf(fr[tid + 256]);
    fb[tid + 512] = f2bf(fr[tid + 512]);

    float s  = v0 + v1 + v2;
    float ss = v0*v0 + v1*v1 + v2*v2;
    __shared__ float red[256], red2[256];
    red[tid] = s; red2[tid] = ss;
    __syncthreads();
    for (int st = 128; st > 0; st >>= 1) {
        if (tid < st) { red[tid] += red[tid + st]; red2[tid] += red2[tid + st]; }
        __syncthreads();
    }
    float mean = red[0] * (1.0f / DIM);
    float var  = red2[0] * (1.0f / DIM) - mean * mean;
    float rstd = rsqrtf(var + 1e-6f);
    u16* qr = q + (size_t)row * DIM;
    qr[tid]       = f2bf((v0 - mean) * rstd * w[tid]       + b[tid]);
    qr[tid + 256] = f2bf((v1 - mean) * rstd * w[tid + 256] + b[tid + 256]);
    qr[tid + 512] = f2bf((v2 - mean) * rstd * w[tid + 512] + b[tid + 512]);
}

// ---------------- all weight transposes in one launch ----------------------
// z=0: vp_w -> vp_wt ; z=1: out_w -> out_wt ; z=2 (x<3): [off|aw|pad] -> oaw_wt
__global__ __launch_bounds__(256) void transpose_all(
        const float* __restrict__ vp_w,  u16* __restrict__ vp_wt,
        const float* __restrict__ out_w, u16* __restrict__ out_wt,
        const float* __restrict__ off_w, const float* __restrict__ aw_w,
        u16* __restrict__ oaw_wt) {
    int z = blockIdx.z;
    if (z == 2 && blockIdx.x >= 3) return;
    __shared__ float tile[32][33];
    int n0 = blockIdx.x * 32, k0 = blockIdx.y * 32;
    int tx = threadIdx.x & 31, ty = threadIdx.x >> 5;
    const float* src = (z == 0) ? vp_w : (z == 1) ? out_w : nullptr;
    u16* dst = (z == 0) ? vp_wt : (z == 1) ? out_wt : oaw_wt;
    #pragma unroll
    for (int r = 0; r < 4; r++) {
        int k = k0 + ty + r * 8, n = n0 + tx;
        float v = 0.0f;
        if (z < 2) {
            v = src[(size_t)k * DIM + n];
        } else {
            if (n < 48) v = off_w[(size_t)k * 48 + n];
            else if (n < 72) v = aw_w[(size_t)k * 24 + (n - 48)];
        }
        tile[ty + r * 8][tx] = v;
    }
    __syncthreads();
    #pragma unroll
    for (int r = 0; r < 4; r++) {
        int nn = ty + r * 8, kk = tx;
        int drow = n0 + nn;
        if (z == 2 && drow >= 80) continue;
        dst[(size_t)drow * KDIM + k0 + kk] = f2bf(tile[kk][nn]);
    }
}

// ---------------- big GEMM: 64x128 tile, BK=64, XCD-swizzled ---------------
// A[M][768]bf16 * Bt[768][768]bf16 ; XOR-swizzled LDS (bank-conflict-free)
__global__ __launch_bounds__(256, 3) void gemm_bt(
        const u16* __restrict__ A, const u16* __restrict__ Bt,
        const float* __restrict__ bias, void* __restrict__ Cout,
        int storeBF16, const float* __restrict__ resid,
        const float* __restrict__ gamma) {
    __shared__ u16 As[BM * BKK];   // 8 KB
    __shared__ u16 Bs[BN * BKK];   // 16 KB
    int tid = threadIdx.x, w = tid >> 6, lane = tid & 63;
    int lm = lane & 15, quad = lane >> 4;
    // XCD-aware swizzle: each XCD owns 16 consecutive m-blocks x all 6 n-blocks
    int b = blockIdx.x;
    int xcd = b & 7, idx = b >> 3;        // idx: 0..95
    int mb = xcd * 16 + idx / NBLK_N;
    int nb = idx % NBLK_N;
    int m0 = mb * BM, n0 = nb * BN;
    int wr = w & 1, wc = w >> 1;

    int srow = lane >> 3;               // 0..7
    int scol = (lane & 7) ^ srow;       // XOR-swizzled source col-block
    const u16* Ab = A + (size_t)m0 * KDIM;
    const u16* Bb = Bt + (size_t)n0 * KDIM;

    f32x4 acc[2][4];
    #pragma unroll
    for (int i = 0; i < 2; i++)
        #pragma unroll
        for (int j = 0; j < 4; j++) acc[i][j] = (f32x4){0.f, 0.f, 0.f, 0.f};

    // precomputed LDS fragment addresses (constant across k-loop)
    const u16* aaddr[2][2];
    const u16* baddr[4][2];
    #pragma unroll
    for (int i = 0; i < 2; i++) {
        int row = wr * 32 + i * 16 + lm;
        #pragma unroll
        for (int kk = 0; kk < 2; kk++)
            aaddr[i][kk] = &As[row * BKK + (((quad + 4 * kk) ^ (row & 7)) << 3)];
    }
    #pragma unroll
    for (int j = 0; j < 4; j++) {
        int row = wc * 64 + j * 16 + lm;
        #pragma unroll
        for (int kk = 0; kk < 2; kk++)
            baddr[j][kk] = &Bs[row * BKK + (((quad + 4 * kk) ^ (row & 7)) << 3)];
    }

    for (int k0 = 0; k0 < KDIM; k0 += BKK) {
        #pragma unroll
        for (int r = 0; r < 2; r++) {
            int row = r * 32 + w * 8 + srow;
            GLD16(Ab + (size_t)row * KDIM + k0 + scol * 8, &As[(r * 32 + w * 8) * BKK]);
        }
        #pragma unroll
        for (int r = 0; r < 4; r++) {
            int row = r * 32 + w * 8 + srow;
            GLD16(Bb + (size_t)row * KDIM + k0 + scol * 8, &Bs[(r * 32 + w * 8) * BKK]);
        }
        __syncthreads();
        #pragma unroll
        for (int kk = 0; kk < 2; kk++) {
            bf16x8 af[2], bf[4];
            #pragma unroll
            for (int i = 0; i < 2; i++) af[i] = *(const bf16x8*)aaddr[i][kk];
            #pragma unroll
            for (int j = 0; j < 4; j++) bf[j] = *(const bf16x8*)baddr[j][kk];
            #pragma unroll
            for (int i = 0; i < 2; i++)
                #pragma unroll
                for (int j = 0; j < 4; j++)
                    acc[i][j] = __builtin_amdgcn_mfma_f32_16x16x32_bf16(af[i], bf[j], acc[i][j], 0, 0, 0);
        }
        __syncthreads();
    }

    #pragma unroll
    for (int j = 0; j < 4; j++) {
        int col = n0 + wc * 64 + j * 16 + lm;
        float bb = bias[col];
        #pragma unroll
        for (int i = 0; i < 2; i++) {
            #pragma unroll
            for (int r = 0; r < 4; r++) {
                int row = m0 + wr * 32 + i * 16 + quad * 4 + r;
                size_t idxo = (size_t)row * DIM + col;
                float v = acc[i][j][r] + bb;
                if (storeBF16) {
                    ((u16*)Cout)[idxo] = f2bf(v);
                } else {
                    ((float*)Cout)[idxo] = resid[idxo] + gamma[col] * v;
                }
            }
        }
    }
}

// ---------------- small GEMM, K-split: q[M][Kpart] * Wt[80][Kpart] ---------
__global__ __launch_bounds__(256, 2) void gemm_small(
        const u16* __restrict__ A, const u16* __restrict__ Bt,
        const float* __restrict__ b0, const float* __restrict__ b1,
        float* __restrict__ C, int M, int K) {
    __shared__ u16 As[64 * 32];
    __shared__ u16 Bs[80 * 32];
    int tid = threadIdx.x, wave = tid >> 6, lane = tid & 63;
    int lm = lane & 15, quad = lane >> 4;
    int m0 = blockIdx.x * 64;
    int part = blockIdx.y;
    int kbase = part * KPART;
    f32x4 acc[5];
    #pragma unroll
    for (int i = 0; i < 5; i++) acc[i] = (f32x4){0.f, 0.f, 0.f, 0.f};
    int lrow = lane >> 2, lcol = (lane & 3) * 8;

    for (int k0 = kbase; k0 < kbase + KPART; k0 += 32) {
        for (int c = wave; c < 9; c += 4) {
            if (c < 4) {
                GLD16(A + (size_t)(m0 + c * 16 + lrow) * K + k0 + lcol, &As[c * 16 * 32]);
            } else {
                GLD16(Bt + (size_t)((c - 4) * 16 + lrow) * K + k0 + lcol, &Bs[(c - 4) * 16 * 32]);
            }
        }
        __syncthreads();
        bf16x8 af = *(const bf16x8*)&As[(wave * 16 + lm) * 32 + quad * 8];
        #pragma unroll
        for (int bn = 0; bn < 5; bn++) {
            bf16x8 bv = *(const bf16x8*)&Bs[(bn * 16 + lm) * 32 + quad * 8];
            acc[bn] = __builtin_amdgcn_mfma_f32_16x16x32_bf16(af, bv, acc[bn], 0, 0, 0);
        }
        __syncthreads();
    }
    float* Cp = C + (size_t)part * M_TOTAL * 80;
    #pragma unroll
    for (int bn = 0; bn < 5; bn++) {
        int col = bn * 16 + lm;
        float bb = 0.0f;
        if (part == 0) bb = (col < 48) ? b0[col] : ((col < 72) ? b1[col - 48] : 0.0f);
        #pragma unroll
        for (int r = 0; r < 4; r++) {
            int row = m0 + wave * 16 + quad * 4 + r;
            Cp[(size_t)row * 80 + col] = acc[bn][r] + bb;
        }
    }
}

// ---------------- softmax(24) + bilinear sampling, predicated loads --------
__global__ __launch_bounds__(384) void sample_kernel(
        const float* __restrict__ oa, const float* __restrict__ refp,
        const u16* __restrict__ v, u16* __restrict__ out) {
    int row = blockIdx.x;
    int b = row >> 12;                 // NQ = 4096
    int tid = threadIdx.x;
    __shared__ float s_w[4][24];
    __shared__ int   s_o[4][24];
    __shared__ float s_e[24];
    if (tid < 24) {
        int h = tid >> 2, p = tid & 3;
        float ox = 0.f, oy = 0.f, lg = 0.f;
        #pragma unroll
        for (int part = 0; part < KSPLIT; part++) {
            const float* pp = oa + (size_t)part * M_TOTAL * 80 + (size_t)row * 80;
            ox += pp[h * 8 + p * 2 + 0];
            oy += pp[h * 8 + p * 2 + 1];
            lg += pp[48 + tid];
        }
        float rx = refp[row * 2 + 0], ry = refp[row * 2 + 1];
        float x = (rx + ox * (1.0f / HW_DIM)) * HW_DIM - 0.5f;
        float y = (ry + oy * (1.0f / HW_DIM)) * HW_DIM - 0.5f;
        float fx = floorf(x), fy = floorf(y);
        int x0 = (int)fx, y0 = (int)fy;
        int x1 = x0 + 1, y1 = y0 + 1;
        float wx = x - fx, wy = y - fy;
        float vx0 = (x0 >= 0 && x0 < HW_DIM) ? 1.f : 0.f;
        float vx1 = (x1 >= 0 && x1 < HW_DIM) ? 1.f : 0.f;
        float vy0 = (y0 >= 0 && y0 < HW_DIM) ? 1.f : 0.f;
        float vy1 = (y1 >= 0 && y1 < HW_DIM) ? 1.f : 0.f;
        int xc0 = min(max(x0, 0), HW_DIM - 1), xc1 = min(max(x1, 0), HW_DIM - 1);
        int yc0 = min(max(y0, 0), HW_DIM - 1), yc1 = min(max(y1, 0), HW_DIM - 1);
        int base = b * NV * DIM;
        s_o[0][tid] = base + (yc0 * HW_DIM + xc0) * DIM;
        s_o[1][tid] = base + (yc0 * HW_DIM + xc1) * DIM;
        s_o[2][tid] = base + (yc1 * HW_DIM + xc0) * DIM;
        s_o[3][tid] = base + (yc1 * HW_DIM + xc1) * DIM;
        s_w[0][tid] = (1.f - wy) * (1.f - wx) * vy0 * vx0;
        s_w[1][tid] = (1.f - wy) * wx * vy0 * vx1;
        s_w[2][tid] = wy * (1.f - wx) * vy1 * vx0;
        s_w[3][tid] = wy * wx * vy1 * vx1;
        s_e[tid] = lg;
        float m = s_e[0];
        #pragma unroll
        for (int i = 1; i < 24; i++) m = fmaxf(m, s_e[i]);
        s_e[tid] = expf(lg - m);
    }
    __syncthreads();
    float ssum = 0.0f;
    #pragma unroll
    for (int i = 0; i < 24; i++) ssum += s_e[i];
    float inv = 1.0f / ssum;

    int h = tid >> 6;
    int d2 = (tid & 63) * 2;
    const u16* vb = v + h * HD + d2;
    float a0 = 0.0f, a1 = 0.0f;
    #pragma unroll
    for (int p = 0; p < 4; p++) {
        int idx = h * 4 + p;
        float aw = s_e[idx] * inv;
        #pragma unroll
        for (int c = 0; c < 4; c++) {
            u32 u = *(const u32*)(vb + s_o[c][idx]);
            float w = aw * s_w[c][idx];
            a0 += w * __uint_as_float(u << 16);
            a1 += w * __uint_as_float(u & 0xffff0000u);
        }
    }
    u32 pack = (u32)f2bf(a0) | ((u32)f2bf(a1) << 16);
    *(u32*)&out[(size_t)row * DIM + h * HD + d2] = pack;
}

extern "C" void kernel_launch(void* const* d_in, const int* in_sizes, int n_in,
                              void* d_out, int out_size, void* d_ws, size_t ws_size,
                              hipStream_t stream) {
    const float* query = (const float*)d_in[0];
    const float* refp  = (const float*)d_in[1];
    const float* feat  = (const float*)d_in[2];
    const float* ln_w  = (const float*)d_in[5];
    const float* ln_b  = (const float*)d_in[6];
    const float* vp_w  = (const float*)d_in[7];
    const float* vp_b  = (const float*)d_in[8];
    const float* off_w = (const float*)d_in[9];
    const float* off_b = (const float*)d_in[10];
    const float* aw_w  = (const float*)d_in[11];
    const float* aw_b  = (const float*)d_in[12];
    const float* out_w = (const float*)d_in[13];
    const float* out_b = (const float*)d_in[14];
    const float* gamma = (const float*)d_in[15];

    const size_t MD = (size_t)M_TOTAL * DIM;      // 6291456
    char* ws = (char*)d_ws;
    u16* q_bf    = (u16*)ws;                 ws += MD * 2;
    u16* feat_bf = (u16*)ws;                 ws += MD * 2;
    u16* v_bf    = (u16*)ws;                 ws += MD * 2;
    u16* s_bf    = (u16*)ws;                 ws += MD * 2;
    u16* vp_wt   = (u16*)ws;                 ws += (size_t)DIM * DIM * 2;
    u16* out_wt  = (u16*)ws;                 ws += (size_t)DIM * DIM * 2;
    u16* oaw_wt  = (u16*)ws;                 ws += (size_t)80 * KDIM * 2;
    float* oa    = (float*)ws;               ws += (size_t)KSPLIT * M_TOTAL * 80 * 4;
    float* out_f = (float*)d_out;

    ln_bf_kernel<<<M_TOTAL, 256, 0, stream>>>(query, ln_w, ln_b, q_bf, feat, feat_bf);
    transpose_all<<<dim3(24, 24, 3), 256, 0, stream>>>(vp_w, vp_wt, out_w, out_wt,
                                                       off_w, aw_w, oaw_wt);
    // value = feat @ vp_w + vp_b   (bf16 out)
    gemm_bt<<<GEMM_GRID, 256, 0, stream>>>(feat_bf, vp_wt, vp_b, v_bf,
                                           1, nullptr, nullptr);
    // offsets + aw logits fused, K split 4 ways
    gemm_small<<<dim3(128, KSPLIT), 256, 0, stream>>>(q_bf, oaw_wt, off_b, aw_b, oa, M_TOTAL, KDIM);
    // sampling
    sample_kernel<<<M_TOTAL, 384, 0, stream>>>(oa, refp, v_bf, s_bf);
    // out = query + gamma * (s @ out_w + out_b)
    gemm_bt<<<GEMM_GRID, 256, 0, stream>>>(s_bf, out_wt, out_b, out_f,
                                           0, query, gamma);
}